// Round 4
// baseline (303.975 us; speedup 1.0000x reference)
//
#include <hip/hip_runtime.h>
#include <math.h>

typedef __attribute__((ext_vector_type(8))) short s8vec;
typedef __attribute__((ext_vector_type(8))) __bf16 bf8vec;
typedef __attribute__((ext_vector_type(4))) float f4vec;

__device__ __forceinline__ unsigned short f2bf(float f) {
  unsigned u = __float_as_uint(f);
  u += 0x7fffu + ((u >> 16) & 1u);  // RNE (finite values only)
  return (unsigned short)(u >> 16);
}

__device__ __forceinline__ f4vec MFMA(s8vec a, s8vec b, f4vec c) {
  return __builtin_amdgcn_mfma_f32_16x16x32_bf16(
      __builtin_bit_cast(bf8vec, a), __builtin_bit_cast(bf8vec, b), c, 0, 0, 0);
}

// tanh-form GELU: |err| vs exact erf-GELU <= ~3e-3, below bf16 rounding of hid.
__device__ __forceinline__ float gelu_t(float v) {
  float u = 0.7978845608028654f * v * (1.f + 0.044715f * v * v);
  u = fminf(fmaxf(u, -15.f), 15.f);
  float e = __expf(2.f * u);
  return 0.5f * v * (1.f + (e - 1.f) / (e + 1.f));
}

// B=32, H=W=64, C=128, S=8, NH=4, HD=32; windows = 2048, tokens = 131072.

// ---------- K0: weight fp32 -> bf16 (qkv | proj | fc1 | fc2 concatenated) ----------
__global__ __launch_bounds__(256) void wconv_k(
    const float* __restrict__ qkvw, const float* __restrict__ projw,
    const float* __restrict__ f1w, const float* __restrict__ f2w,
    short* __restrict__ out) {
  int i = blockIdx.x * 256 + threadIdx.x;  // grid covers 196608 exactly
  float v;
  if (i < 49152)        v = qkvw[i];
  else if (i < 65536)   v = projw[i - 49152];
  else if (i < 131072)  v = f1w[i - 65536];
  else                  v = f2w[i - 131072];
  out[i] = (short)f2bf(v);
}

// ---------- K1: fully fused Swin block. 1 block = 1 window, wave = head. ----------
// LDS 64 KB -> 2 blocks/CU (8 waves). VGPRs uncapped (2 waves/SIMD -> up to 256).
__global__ __launch_bounds__(256) void swin_k(
    const float* __restrict__ x, const float* __restrict__ ln1w,
    const float* __restrict__ ln1b, const short* __restrict__ wq,
    const float* __restrict__ qkvb, const short* __restrict__ wp,
    const float* __restrict__ projb, const float* __restrict__ ln2w,
    const float* __restrict__ ln2b, const short* __restrict__ w1,
    const float* __restrict__ fc1b, const short* __restrict__ w2,
    const float* __restrict__ fc2b, float* __restrict__ out) {
  __shared__ short lds[32768];           // 64 KB
  short* xs = lds;                       // [64][128] swz: LN1-out, later LN2-out
  short* qs = lds + 8192;                // q [64][128]; later P (heads 0..1) / cs
  short* ks = lds + 16384;               // k [64][128]; later P (2..3) / stats
  short* vt = lds + 24576;               // vT [128][64]; later attn-out [64][128]
  float* statS = (float*)(lds + 16384);  // 256 f (row partial sums, [row][wave])
  float* statQ = statS + 256;            // 256 f (row partial sumsq)
  short* cs = qs;                        // MLP chunk [64][128] swz

  const int wi = blockIdx.x, tid = threadIdx.x;
  const int bb = wi >> 6, hy = (wi >> 3) & 7, wx = wi & 7;
  const f4vec fz = {0.f, 0.f, 0.f, 0.f};

  // ---- phase A: LN1 with roll+window gather (4 lanes per token) ----
  {
    const int t = tid >> 2, sub = tid & 3;
    const int sy = t >> 3, sx = t & 7;
    const int py = (sy * 8 + hy + 8) & 63, px = (sx * 8 + wx + 8) & 63;
    const float* xr = x + ((size_t)(bb * 4096 + py * 64 + px)) * 128 + sub * 32;
    float vv[32];
    float s = 0.f, sq = 0.f;
#pragma unroll
    for (int j = 0; j < 8; ++j) {
      float4 f = ((const float4*)xr)[j];
      vv[j * 4 + 0] = f.x; vv[j * 4 + 1] = f.y;
      vv[j * 4 + 2] = f.z; vv[j * 4 + 3] = f.w;
      s += f.x + f.y + f.z + f.w;
      sq += f.x * f.x + f.y * f.y + f.z * f.z + f.w * f.w;
    }
    s += __shfl_xor(s, 1);  s += __shfl_xor(s, 2);
    sq += __shfl_xor(sq, 1); sq += __shfl_xor(sq, 2);
    const float mean = s * 0.0078125f;
    const float rs = rsqrtf(sq * 0.0078125f - mean * mean + 1e-5f);
#pragma unroll
    for (int j8 = 0; j8 < 4; ++j8) {
      s8vec p;
#pragma unroll
      for (int e = 0; e < 8; ++e) {
        int c = sub * 32 + j8 * 8 + e;
        p[e] = (short)f2bf((vv[j8 * 8 + e] - mean) * rs * ln1w[c] + ln1b[c]);
      }
      *(s8vec*)(xs + t * 128 + (((sub * 4 + j8) ^ (t & 7)) << 3)) = p;
    }
  }
  __syncthreads();  // #1: xs (LN1) ready

  const int h = tid >> 6, lane = tid & 63, g = lane >> 4, li = lane & 15;
  const int sl = li & 7;

  // ---- phase B: QKV for own head (64 x 96), W frags straight from L2 ----
  f4vec acc[4][6];
#pragma unroll
  for (int mi = 0; mi < 4; ++mi)
#pragma unroll
    for (int ng = 0; ng < 6; ++ng) acc[mi][ng] = fz;
#pragma unroll
  for (int kk = 0; kk < 4; ++kk) {
    s8vec a0[4];
#pragma unroll
    for (int mi = 0; mi < 4; ++mi)
      a0[mi] = *(const s8vec*)(xs + (mi * 16 + li) * 128 + (((kk * 4 + g) ^ sl) << 3));
#pragma unroll
    for (int ng = 0; ng < 6; ++ng) {
      s8vec bw = *(const s8vec*)(wq + (size_t)(h * 96 + ng * 16 + li) * 128 + kk * 32 + g * 8);
#pragma unroll
      for (int mi = 0; mi < 4; ++mi) acc[mi][ng] = MFMA(a0[mi], bw, acc[mi][ng]);
    }
  }
  // scatter q/k/vT to LDS (column-disjoint per wave; same-wave LDS is in-order)
#pragma unroll
  for (int ng = 0; ng < 6; ++ng) {
    const int tt = ng >> 1;             // 0=q 1=k 2=v (compile-time)
    const int hd = (ng & 1) * 16 + li;  // 0..31
    const float bias = qkvb[h * 96 + ng * 16 + li];
#pragma unroll
    for (int mi = 0; mi < 4; ++mi)
#pragma unroll
      for (int r = 0; r < 4; ++r) {
        int i = mi * 16 + g * 4 + r;
        short bv = (short)f2bf(acc[mi][ng][r] + bias);
        if (tt == 0)
          qs[i * 128 + (((h * 4 + (hd >> 3)) ^ (i & 7)) << 3) + (hd & 7)] = bv;
        else if (tt == 1)
          ks[i * 128 + (((h * 4 + (hd >> 3)) ^ (i & 7)) << 3) + (hd & 7)] = bv;
        else
          vt[(h * 32 + hd) * 64 + (((i >> 3) ^ (hd & 7)) << 3) + (i & 7)] = bv;
      }
  }

  // load q,k fragments BEFORE P overlays q/k region (own-wave cells only)
  s8vec qf[4], kf[4];
#pragma unroll
  for (int mi = 0; mi < 4; ++mi)
    qf[mi] = *(const s8vec*)(qs + (mi * 16 + li) * 128 + (((h * 4 + g) ^ sl) << 3));
#pragma unroll
  for (int ni = 0; ni < 4; ++ni)
    kf[ni] = *(const s8vec*)(ks + (ni * 16 + li) * 128 + (((h * 4 + g) ^ sl) << 3));
  __syncthreads();  // #2: all q/k reads done; P overlay now safe

  // ---- phase C: QK^T, softmax, P, PV ----
  f4vec e[4][4];
#pragma unroll
  for (int mi = 0; mi < 4; ++mi)
#pragma unroll
    for (int ni = 0; ni < 4; ++ni) e[mi][ni] = fz;
#pragma unroll
  for (int mi = 0; mi < 4; ++mi)
#pragma unroll
    for (int ni = 0; ni < 4; ++ni) e[mi][ni] = MFMA(qf[mi], kf[ni], e[mi][ni]);

  const float scale = 0.17677669529663687f;  // 1/sqrt(32); "+1.0" cancels in softmax
  short* Pm = lds + 8192 + h * 4096;         // 64x64 bf16, swizzled (own-wave)
#pragma unroll
  for (int mi = 0; mi < 4; ++mi)
#pragma unroll
    for (int r = 0; r < 4; ++r) {
      float mx = e[mi][0][r];
#pragma unroll
      for (int ni = 1; ni < 4; ++ni) mx = fmaxf(mx, e[mi][ni][r]);
#pragma unroll
      for (int m = 1; m < 16; m <<= 1) mx = fmaxf(mx, __shfl_xor(mx, m));
      float pr[4], sm = 0.f;
#pragma unroll
      for (int ni = 0; ni < 4; ++ni) {
        pr[ni] = __expf((e[mi][ni][r] - mx) * scale);
        sm += pr[ni];
      }
#pragma unroll
      for (int m = 1; m < 16; m <<= 1) sm += __shfl_xor(sm, m);
      float inv = 1.0f / sm;
      int i = mi * 16 + g * 4 + r;
#pragma unroll
      for (int ni = 0; ni < 4; ++ni) {
        int j = ni * 16 + li;
        Pm[i * 64 + (((j >> 3) ^ (i & 7)) << 3) + (j & 7)] = (short)f2bf(pr[ni] * inv);
      }
    }

  s8vec vf[2][2];
#pragma unroll
  for (int di = 0; di < 2; ++di)
#pragma unroll
    for (int kk = 0; kk < 2; ++kk)
      vf[di][kk] = *(const s8vec*)(vt + (h * 32 + di * 16 + li) * 64 + (((kk * 4 + g) ^ sl) << 3));
  __syncthreads();  // #2.5: all vf loads done; attn-out overlay of vt now safe

  f4vec o[4][2];
#pragma unroll
  for (int mi = 0; mi < 4; ++mi)
#pragma unroll
    for (int di = 0; di < 2; ++di) o[mi][di] = fz;
#pragma unroll
  for (int kk = 0; kk < 2; ++kk)
#pragma unroll
    for (int mi = 0; mi < 4; ++mi) {
      s8vec pa = *(const s8vec*)(Pm + (mi * 16 + li) * 64 + (((kk * 4 + g) ^ sl) << 3));
#pragma unroll
      for (int di = 0; di < 2; ++di) o[mi][di] = MFMA(pa, vf[di][kk], o[mi][di]);
    }

  // attn-out -> vt region (overlay), [64][128] swz
#pragma unroll
  for (int mi = 0; mi < 4; ++mi)
#pragma unroll
    for (int di = 0; di < 2; ++di)
#pragma unroll
      for (int r = 0; r < 4; ++r) {
        int i = mi * 16 + g * 4 + r;
        int c8 = h * 4 + di * 2 + (li >> 3);
        vt[i * 128 + ((c8 ^ (i & 7)) << 3) + sl] = (short)f2bf(o[mi][di][r]);
      }
  __syncthreads();  // #3: attn-out visible; P dead

  // ---- phase D: proj + bias + residual(x) -> msa (registers only) ----
  f4vec pacc[4][2];
#pragma unroll
  for (int mi = 0; mi < 4; ++mi)
#pragma unroll
    for (int nj = 0; nj < 2; ++nj) pacc[mi][nj] = fz;
#pragma unroll
  for (int kk = 0; kk < 4; ++kk) {
    s8vec a0[4];
#pragma unroll
    for (int mi = 0; mi < 4; ++mi)
      a0[mi] = *(const s8vec*)(vt + (mi * 16 + li) * 128 + (((kk * 4 + g) ^ sl) << 3));
#pragma unroll
    for (int nj = 0; nj < 2; ++nj) {
      s8vec bw = *(const s8vec*)(wp + (size_t)(h * 32 + nj * 16 + li) * 128 + kk * 32 + g * 8);
#pragma unroll
      for (int mi = 0; mi < 4; ++mi) pacc[mi][nj] = MFMA(a0[mi], bw, pacc[mi][nj]);
    }
  }
  float msa_v[4][2][4];
#pragma unroll
  for (int nj = 0; nj < 2; ++nj) {
    const int col = h * 32 + nj * 16 + li;
    const float pb = projb[col];
#pragma unroll
    for (int mi = 0; mi < 4; ++mi)
#pragma unroll
      for (int r = 0; r < 4; ++r) {
        int i = mi * 16 + g * 4 + r;
        int sy = i >> 3, sx = i & 7;
        int py = (sy * 8 + hy + 8) & 63, px = (sx * 8 + wx + 8) & 63;
        size_t dst = ((size_t)(bb * 4096 + py * 64 + px)) * 128 + col;
        msa_v[mi][nj][r] = x[dst] + pacc[mi][nj][r] + pb;
      }
  }

  // ---- phase E: LN2 row stats (cross-wave via 2 KB LDS) + normalize -> xs ----
#pragma unroll
  for (int mi = 0; mi < 4; ++mi)
#pragma unroll
    for (int r = 0; r < 4; ++r) {
      float s = msa_v[mi][0][r] + msa_v[mi][1][r];
      float q = msa_v[mi][0][r] * msa_v[mi][0][r] + msa_v[mi][1][r] * msa_v[mi][1][r];
#pragma unroll
      for (int m = 1; m < 16; m <<= 1) {
        s += __shfl_xor(s, m);
        q += __shfl_xor(q, m);
      }
      if (li == 0) {
        int i = mi * 16 + g * 4 + r;
        statS[i * 4 + h] = s;
        statQ[i * 4 + h] = q;
      }
    }
  __syncthreads();  // #4: stats visible (qs/ks regions otherwise dead)

  {
    const float lw0 = ln2w[h * 32 + li],      lb0 = ln2b[h * 32 + li];
    const float lw1 = ln2w[h * 32 + 16 + li], lb1 = ln2b[h * 32 + 16 + li];
#pragma unroll
    for (int mi = 0; mi < 4; ++mi)
#pragma unroll
      for (int r = 0; r < 4; ++r) {
        int i = mi * 16 + g * 4 + r;
        float4 s4 = *(const float4*)(statS + i * 4);
        float4 q4 = *(const float4*)(statQ + i * 4);
        float mean = (s4.x + s4.y + s4.z + s4.w) * 0.0078125f;
        float var = (q4.x + q4.y + q4.z + q4.w) * 0.0078125f - mean * mean;
        float rstd = rsqrtf(var + 1e-5f);
        float n0 = (msa_v[mi][0][r] - mean) * rstd * lw0 + lb0;
        float n1 = (msa_v[mi][1][r] - mean) * rstd * lw1 + lb1;
        xs[i * 128 + (((h * 4 + 0 * 2 + (li >> 3)) ^ (i & 7)) << 3) + sl] = (short)f2bf(n0);
        xs[i * 128 + (((h * 4 + 1 * 2 + (li >> 3)) ^ (i & 7)) << 3) + sl] = (short)f2bf(n1);
      }
  }
  __syncthreads();  // #5: xs (LN2) ready; cs overlay of qs safe

  // ---- phase F: MLP, hid chunked 4 x 128 cols through one 16 KB LDS buffer ----
  f4vec facc[4][2];
#pragma unroll
  for (int mi = 0; mi < 4; ++mi)
#pragma unroll
    for (int nj = 0; nj < 2; ++nj) facc[mi][nj] = fz;

  for (int c = 0; c < 4; ++c) {
    // FC1 chunk: hid cols c*128 + h*32 + {nj*16+li}
    f4vec a1[4][2];
#pragma unroll
    for (int mi = 0; mi < 4; ++mi)
#pragma unroll
      for (int nj = 0; nj < 2; ++nj) a1[mi][nj] = fz;
#pragma unroll
    for (int kk = 0; kk < 4; ++kk) {
      s8vec a0[4];
#pragma unroll
      for (int mi = 0; mi < 4; ++mi)
        a0[mi] = *(const s8vec*)(xs + (mi * 16 + li) * 128 + (((kk * 4 + g) ^ sl) << 3));
#pragma unroll
      for (int nj = 0; nj < 2; ++nj) {
        s8vec bw = *(const s8vec*)(w1 + (size_t)(c * 128 + h * 32 + nj * 16 + li) * 128 + kk * 32 + g * 8);
#pragma unroll
        for (int mi = 0; mi < 4; ++mi) a1[mi][nj] = MFMA(a0[mi], bw, a1[mi][nj]);
      }
    }
    const float b10 = fc1b[c * 128 + h * 32 + li];
    const float b11 = fc1b[c * 128 + h * 32 + 16 + li];
#pragma unroll
    for (int nj = 0; nj < 2; ++nj) {
      const int c8 = h * 4 + nj * 2 + (li >> 3);
      const float b1 = nj ? b11 : b10;
#pragma unroll
      for (int mi = 0; mi < 4; ++mi)
#pragma unroll
        for (int r = 0; r < 4; ++r) {
          int i = mi * 16 + g * 4 + r;
          cs[i * 128 + ((c8 ^ (i & 7)) << 3) + sl] = (short)f2bf(gelu_t(a1[mi][nj][r] + b1));
        }
    }
    __syncthreads();  // #6c: chunk visible

    // FC2 partial: out cols h*32+{nj*16+li}, K = chunk's 128
#pragma unroll
    for (int kk = 0; kk < 4; ++kk) {
      s8vec a0[4];
#pragma unroll
      for (int mi = 0; mi < 4; ++mi)
        a0[mi] = *(const s8vec*)(cs + (mi * 16 + li) * 128 + (((kk * 4 + g) ^ sl) << 3));
#pragma unroll
      for (int nj = 0; nj < 2; ++nj) {
        s8vec bw = *(const s8vec*)(w2 + (size_t)(h * 32 + nj * 16 + li) * 512 + c * 128 + kk * 32 + g * 8);
#pragma unroll
        for (int mi = 0; mi < 4; ++mi) facc[mi][nj] = MFMA(a0[mi], bw, facc[mi][nj]);
      }
    }
    if (c != 3) __syncthreads();  // #7c: chunk reads done before overwrite
  }

  // ---- phase G: final write: out = msa + fc2 + fc2b (single store, un-permuted) ----
#pragma unroll
  for (int nj = 0; nj < 2; ++nj) {
    const int col = h * 32 + nj * 16 + li;
    const float fb = fc2b[col];
#pragma unroll
    for (int mi = 0; mi < 4; ++mi)
#pragma unroll
      for (int r = 0; r < 4; ++r) {
        int i = mi * 16 + g * 4 + r;
        int sy = i >> 3, sx = i & 7;
        int py = (sy * 8 + hy + 8) & 63, px = (sx * 8 + wx + 8) & 63;
        size_t dst = ((size_t)(bb * 4096 + py * 64 + px)) * 128 + col;
        out[dst] = msa_v[mi][nj][r] + facc[mi][nj][r] + fb;
      }
  }
}

// ---------- launch ----------
extern "C" void kernel_launch(void* const* d_in, const int* in_sizes, int n_in,
                              void* d_out, int out_size, void* d_ws, size_t ws_size,
                              hipStream_t stream) {
  const float* x     = (const float*)d_in[0];
  const float* ln1w  = (const float*)d_in[1];
  const float* ln1b  = (const float*)d_in[2];
  const float* qkvw  = (const float*)d_in[3];
  const float* qkvb  = (const float*)d_in[4];
  const float* projw = (const float*)d_in[5];
  const float* projb = (const float*)d_in[6];
  const float* ln2w  = (const float*)d_in[7];
  const float* ln2b  = (const float*)d_in[8];
  const float* fc1w  = (const float*)d_in[9];
  const float* fc1b  = (const float*)d_in[10];
  const float* fc2w  = (const float*)d_in[11];
  const float* fc2b  = (const float*)d_in[12];

  short* wb = (short*)d_ws;  // bf16 weights: qkv@0, proj@49152, fc1@65536, fc2@131072
  float* out = (float*)d_out;

  wconv_k<<<768, 256, 0, stream>>>(qkvw, projw, fc1w, fc2w, wb);
  swin_k<<<2048, 256, 0, stream>>>(x, ln1w, ln1b, wb, qkvb, wb + 49152, projb,
                                   ln2w, ln2b, wb + 65536, fc1b, wb + 131072,
                                   fc2b, out);
}

// Round 6
// 293.196 us; speedup vs baseline: 1.0368x; 1.0368x over previous
//
#include <hip/hip_runtime.h>
#include <math.h>

typedef __attribute__((ext_vector_type(8))) short s8vec;
typedef __attribute__((ext_vector_type(8))) __bf16 bf8vec;
typedef __attribute__((ext_vector_type(4))) float f4vec;

__device__ __forceinline__ unsigned short f2bf(float f) {
  unsigned u = __float_as_uint(f);
  u += 0x7fffu + ((u >> 16) & 1u);  // RNE (finite values only)
  return (unsigned short)(u >> 16);
}
__device__ __forceinline__ float bf2f(unsigned short u) {
  return __uint_as_float(((unsigned)u) << 16);
}

__device__ __forceinline__ f4vec MFMA(s8vec a, s8vec b, f4vec c) {
  return __builtin_amdgcn_mfma_f32_16x16x32_bf16(
      __builtin_bit_cast(bf8vec, a), __builtin_bit_cast(bf8vec, b), c, 0, 0, 0);
}

// tanh-form GELU: |err| vs exact erf-GELU <= ~3e-3, below bf16 rounding of hid.
__device__ __forceinline__ float gelu_t(float v) {
  float u = 0.7978845608028654f * v * (1.f + 0.044715f * v * v);
  u = fminf(fmaxf(u, -15.f), 15.f);
  float e = __expf(2.f * u);
  return 0.5f * v * (1.f + (e - 1.f) / (e + 1.f));
}

// B=32, H=W=64, C=128, S=8, NH=4, HD=32; windows = 2048, tokens = 131072.

// ---------- K0: weight fp32 -> bf16 (qkv | proj | fc1 | fc2 concatenated) ----------
__global__ __launch_bounds__(256) void wconv_k(
    const float* __restrict__ qkvw, const float* __restrict__ projw,
    const float* __restrict__ f1w, const float* __restrict__ f2w,
    short* __restrict__ out) {
  int i = blockIdx.x * 256 + threadIdx.x;  // grid covers 196608 exactly
  float v;
  if (i < 49152)        v = qkvw[i];
  else if (i < 65536)   v = projw[i - 49152];
  else if (i < 131072)  v = f1w[i - 65536];
  else                  v = f2w[i - 131072];
  out[i] = (short)f2bf(v);
}

// ---------- K1: fully fused Swin block, 32 KB LDS. 1 block = 1 window. ----------
// LDS regions (short idx): [0,8192) xs: LN1-out -> attn-out -> LN2-out
//                          [8192,16384) per-wave scratch (2048 ea) -> stats -> cs
//                          P overlay: head h at [h*4096, h*4096+4096) after barrier #2
__global__ __launch_bounds__(256) void swin_k(
    const float* __restrict__ x, const float* __restrict__ ln1w,
    const float* __restrict__ ln1b, const short* __restrict__ wq,
    const float* __restrict__ qkvb, const short* __restrict__ wp,
    const float* __restrict__ projb, const float* __restrict__ ln2w,
    const float* __restrict__ ln2b, const short* __restrict__ w1,
    const float* __restrict__ fc1b, const short* __restrict__ w2,
    const float* __restrict__ fc2b, float* __restrict__ out) {
  __shared__ short lds[16384];  // 32 KB
  short* xs = lds;
  float* statS = (float*)(lds + 8192);  // 256 f (alive only in phase E)
  float* statQ = statS + 256;
  short* cs = lds + 8192;               // MLP hid chunk [64][128]

  const int wi = blockIdx.x, tid = threadIdx.x;
  const int bb = wi >> 6, hy = (wi >> 3) & 7, wx = wi & 7;
  const f4vec fz = {0.f, 0.f, 0.f, 0.f};

  // ---- phase A: LN1 with roll+window gather (4 lanes per token) ----
  {
    const int t = tid >> 2, sub = tid & 3;
    const int sy = t >> 3, sx = t & 7;
    const int py = (sy * 8 + hy + 8) & 63, px = (sx * 8 + wx + 8) & 63;
    const float* xr = x + ((size_t)(bb * 4096 + py * 64 + px)) * 128 + sub * 32;
    float vv[32];
    float s = 0.f, sq = 0.f;
#pragma unroll
    for (int j = 0; j < 8; ++j) {
      float4 f = ((const float4*)xr)[j];
      vv[j * 4 + 0] = f.x; vv[j * 4 + 1] = f.y;
      vv[j * 4 + 2] = f.z; vv[j * 4 + 3] = f.w;
      s += f.x + f.y + f.z + f.w;
      sq += f.x * f.x + f.y * f.y + f.z * f.z + f.w * f.w;
    }
    s += __shfl_xor(s, 1);  s += __shfl_xor(s, 2);
    sq += __shfl_xor(sq, 1); sq += __shfl_xor(sq, 2);
    const float mean = s * 0.0078125f;
    const float rs = rsqrtf(sq * 0.0078125f - mean * mean + 1e-5f);
#pragma unroll
    for (int j8 = 0; j8 < 4; ++j8) {
      s8vec p;
#pragma unroll
      for (int e = 0; e < 8; ++e) {
        int c = sub * 32 + j8 * 8 + e;
        p[e] = (short)f2bf((vv[j8 * 8 + e] - mean) * rs * ln1w[c] + ln1b[c]);
      }
      *(s8vec*)(xs + t * 128 + (((sub * 4 + j8) ^ (t & 7)) << 3)) = p;
    }
  }
  __syncthreads();  // #1: xs (LN1) ready

  const int h = tid >> 6, lane = tid & 63, g = lane >> 4, li = lane & 15;
  const int sl = li & 7;
  short* SCR = lds + 8192 + h * 2048;  // per-wave private scratch (4 KB)
  short* Pm = lds + h * 4096;          // per-head P [64][64] (after barrier #2)

  // ---- phase B: QKV via per-wave scratch transpose, 3 sequential cycles ----
  s8vec qf[4], kf[4], vf[2][2];
  auto qk_cycle = [&](const int T, s8vec* fr) {  // T=0 q, T=1 k
    f4vec acc[4][2];
#pragma unroll
    for (int mi = 0; mi < 4; ++mi) { acc[mi][0] = fz; acc[mi][1] = fz; }
#pragma unroll
    for (int kk = 0; kk < 4; ++kk) {
      s8vec a0[4];
#pragma unroll
      for (int mi = 0; mi < 4; ++mi)
        a0[mi] = *(const s8vec*)(xs + (mi * 16 + li) * 128 + (((kk * 4 + g) ^ sl) << 3));
      s8vec bw[2];
#pragma unroll
      for (int n = 0; n < 2; ++n)
        bw[n] = *(const s8vec*)(wq + (size_t)(h * 96 + T * 32 + n * 16 + li) * 128 + kk * 32 + g * 8);
#pragma unroll
      for (int n = 0; n < 2; ++n)
#pragma unroll
        for (int mi = 0; mi < 4; ++mi) acc[mi][n] = MFMA(a0[mi], bw[n], acc[mi][n]);
    }
    // scatter [token][hd(32)] granule-swizzled; same-wave LDS is in-order
#pragma unroll
    for (int n = 0; n < 2; ++n) {
      const float bias = qkvb[h * 96 + T * 32 + n * 16 + li];
#pragma unroll
      for (int mi = 0; mi < 4; ++mi)
#pragma unroll
        for (int r = 0; r < 4; ++r) {
          int t = mi * 16 + g * 4 + r;
          SCR[t * 32 + (((2 * n + (li >> 3)) ^ r) << 3) + sl] =
              (short)f2bf(acc[mi][n][r] + bias);
        }
    }
#pragma unroll
    for (int mi = 0; mi < 4; ++mi)
      fr[mi] = *(const s8vec*)(SCR + (mi * 16 + li) * 32 + ((g ^ (li & 3)) << 3));
  };
  qk_cycle(0, qf);
  qk_cycle(1, kf);
  {  // V cycle: layout [d(32)][token(64)] for PV B-fragments
    f4vec acc[4][2];
#pragma unroll
    for (int mi = 0; mi < 4; ++mi) { acc[mi][0] = fz; acc[mi][1] = fz; }
#pragma unroll
    for (int kk = 0; kk < 4; ++kk) {
      s8vec a0[4];
#pragma unroll
      for (int mi = 0; mi < 4; ++mi)
        a0[mi] = *(const s8vec*)(xs + (mi * 16 + li) * 128 + (((kk * 4 + g) ^ sl) << 3));
      s8vec bw[2];
#pragma unroll
      for (int n = 0; n < 2; ++n)
        bw[n] = *(const s8vec*)(wq + (size_t)(h * 96 + 64 + n * 16 + li) * 128 + kk * 32 + g * 8);
#pragma unroll
      for (int n = 0; n < 2; ++n)
#pragma unroll
        for (int mi = 0; mi < 4; ++mi) acc[mi][n] = MFMA(a0[mi], bw[n], acc[mi][n]);
    }
#pragma unroll
    for (int n = 0; n < 2; ++n) {
      const float bias = qkvb[h * 96 + 64 + n * 16 + li];
#pragma unroll
      for (int mi = 0; mi < 4; ++mi)
#pragma unroll
        for (int r = 0; r < 4; ++r) {
          int t = mi * 16 + g * 4 + r, d = n * 16 + li;
          SCR[d * 64 + (((t >> 3) ^ (li & 3)) << 3) + (t & 7)] =
              (short)f2bf(acc[mi][n][r] + bias);
        }
    }
#pragma unroll
    for (int di = 0; di < 2; ++di)
#pragma unroll
      for (int kk = 0; kk < 2; ++kk)
        vf[di][kk] = *(const s8vec*)(SCR + (di * 16 + li) * 64 + (((kk * 4 + g) ^ (li & 3)) << 3));
  }
  __syncthreads();  // #2: all xs/scratch reads done; P overlay now safe

  // ---- phase C: QK^T (mi-halved) + softmax + P store + PV ----
  const float scale = 0.17677669529663687f;  // 1/sqrt(32); "+1.0" cancels
#pragma unroll
  for (int hf = 0; hf < 2; ++hf) {
    f4vec e[2][4];
#pragma unroll
    for (int m2 = 0; m2 < 2; ++m2)
#pragma unroll
      for (int ni = 0; ni < 4; ++ni) e[m2][ni] = fz;
#pragma unroll
    for (int m2 = 0; m2 < 2; ++m2)
#pragma unroll
      for (int ni = 0; ni < 4; ++ni)
        e[m2][ni] = MFMA(qf[hf * 2 + m2], kf[ni], e[m2][ni]);
#pragma unroll
    for (int m2 = 0; m2 < 2; ++m2)
#pragma unroll
      for (int r = 0; r < 4; ++r) {
        float mx = e[m2][0][r];
#pragma unroll
        for (int ni = 1; ni < 4; ++ni) mx = fmaxf(mx, e[m2][ni][r]);
#pragma unroll
        for (int m = 1; m < 16; m <<= 1) mx = fmaxf(mx, __shfl_xor(mx, m));
        float pr[4], sm = 0.f;
#pragma unroll
        for (int ni = 0; ni < 4; ++ni) {
          pr[ni] = __expf((e[m2][ni][r] - mx) * scale);
          sm += pr[ni];
        }
#pragma unroll
        for (int m = 1; m < 16; m <<= 1) sm += __shfl_xor(sm, m);
        float inv = 1.0f / sm;
        int i = (hf * 2 + m2) * 16 + g * 4 + r;
#pragma unroll
        for (int ni = 0; ni < 4; ++ni) {
          int j = ni * 16 + li;
          Pm[i * 64 + (((j >> 3) ^ (i & 7)) << 3) + (j & 7)] = (short)f2bf(pr[ni] * inv);
        }
      }
  }
  f4vec o[4][2];
#pragma unroll
  for (int mi = 0; mi < 4; ++mi) { o[mi][0] = fz; o[mi][1] = fz; }
#pragma unroll
  for (int kk = 0; kk < 2; ++kk)
#pragma unroll
    for (int mi = 0; mi < 4; ++mi) {
      s8vec pa = *(const s8vec*)(Pm + (mi * 16 + li) * 64 + (((kk * 4 + g) ^ sl) << 3));
#pragma unroll
      for (int di = 0; di < 2; ++di) o[mi][di] = MFMA(pa, vf[di][kk], o[mi][di]);
    }
  __syncthreads();  // #3: all PV done; P dead; attn-out overlay of xs safe

#pragma unroll
  for (int mi = 0; mi < 4; ++mi)
#pragma unroll
    for (int di = 0; di < 2; ++di)
#pragma unroll
      for (int r = 0; r < 4; ++r) {
        int i = mi * 16 + g * 4 + r;
        int c8 = h * 4 + di * 2 + (li >> 3);
        xs[i * 128 + ((c8 ^ (i & 7)) << 3) + sl] = (short)f2bf(o[mi][di][r]);
      }
  __syncthreads();  // #4: attn-out visible

  // ---- phase D: proj + bias + residual(x) -> msa (registers) ----
  f4vec pacc[4][2];
#pragma unroll
  for (int mi = 0; mi < 4; ++mi) { pacc[mi][0] = fz; pacc[mi][1] = fz; }
#pragma unroll
  for (int kk = 0; kk < 4; ++kk) {
    s8vec a0[4];
#pragma unroll
    for (int mi = 0; mi < 4; ++mi)
      a0[mi] = *(const s8vec*)(xs + (mi * 16 + li) * 128 + (((kk * 4 + g) ^ sl) << 3));
    s8vec bw[2];
#pragma unroll
    for (int nj = 0; nj < 2; ++nj)
      bw[nj] = *(const s8vec*)(wp + (size_t)(h * 32 + nj * 16 + li) * 128 + kk * 32 + g * 8);
#pragma unroll
    for (int nj = 0; nj < 2; ++nj)
#pragma unroll
      for (int mi = 0; mi < 4; ++mi) pacc[mi][nj] = MFMA(a0[mi], bw[nj], pacc[mi][nj]);
  }
  float msa_v[4][2][4];
#pragma unroll
  for (int nj = 0; nj < 2; ++nj) {
    const int col = h * 32 + nj * 16 + li;
    const float pb = projb[col];
#pragma unroll
    for (int mi = 0; mi < 4; ++mi)
#pragma unroll
      for (int r = 0; r < 4; ++r) {
        int i = mi * 16 + g * 4 + r;
        int sy = i >> 3, sx = i & 7;
        int py = (sy * 8 + hy + 8) & 63, px = (sx * 8 + wx + 8) & 63;
        size_t dst = ((size_t)(bb * 4096 + py * 64 + px)) * 128 + col;
        msa_v[mi][nj][r] = x[dst] + pacc[mi][nj][r] + pb;
      }
  }

  // ---- phase E: LN2 stats (cross-wave, 2 KB in dead scratch) + normalize ----
#pragma unroll
  for (int mi = 0; mi < 4; ++mi)
#pragma unroll
    for (int r = 0; r < 4; ++r) {
      float s = msa_v[mi][0][r] + msa_v[mi][1][r];
      float q = msa_v[mi][0][r] * msa_v[mi][0][r] + msa_v[mi][1][r] * msa_v[mi][1][r];
#pragma unroll
      for (int m = 1; m < 16; m <<= 1) {
        s += __shfl_xor(s, m);
        q += __shfl_xor(q, m);
      }
      if (li == 0) {
        int i = mi * 16 + g * 4 + r;
        statS[i * 4 + h] = s;
        statQ[i * 4 + h] = q;
      }
    }
  __syncthreads();  // #5: stats visible; all attn-out reads (D) done

  unsigned msa_p[4][2][2];  // msa packed as bf16 pairs (r0|r1, r2|r3)
  {
    const float lw0 = ln2w[h * 32 + li],      lb0 = ln2b[h * 32 + li];
    const float lw1 = ln2w[h * 32 + 16 + li], lb1 = ln2b[h * 32 + 16 + li];
#pragma unroll
    for (int mi = 0; mi < 4; ++mi)
#pragma unroll
      for (int r = 0; r < 4; ++r) {
        int i = mi * 16 + g * 4 + r;
        float4 s4 = *(const float4*)(statS + i * 4);
        float4 q4 = *(const float4*)(statQ + i * 4);
        float mean = (s4.x + s4.y + s4.z + s4.w) * 0.0078125f;
        float var = (q4.x + q4.y + q4.z + q4.w) * 0.0078125f - mean * mean;
        float rstd = rsqrtf(var + 1e-5f);
        float n0 = (msa_v[mi][0][r] - mean) * rstd * lw0 + lb0;
        float n1 = (msa_v[mi][1][r] - mean) * rstd * lw1 + lb1;
        xs[i * 128 + (((h * 4 + (li >> 3)) ^ (i & 7)) << 3) + sl] = (short)f2bf(n0);
        xs[i * 128 + (((h * 4 + 2 + (li >> 3)) ^ (i & 7)) << 3) + sl] = (short)f2bf(n1);
      }
#pragma unroll
    for (int mi = 0; mi < 4; ++mi)
#pragma unroll
      for (int nj = 0; nj < 2; ++nj)
#pragma unroll
        for (int p = 0; p < 2; ++p)
          msa_p[mi][nj][p] = (unsigned)f2bf(msa_v[mi][nj][2 * p]) |
                             ((unsigned)f2bf(msa_v[mi][nj][2 * p + 1]) << 16);
  }
  __syncthreads();  // #6: xs (LN2) ready; stats dead; cs overlay safe

  // ---- phase F: MLP, hid chunked 4 x 128 cols through cs (16 KB) ----
  f4vec facc[4][2];
#pragma unroll
  for (int mi = 0; mi < 4; ++mi) { facc[mi][0] = fz; facc[mi][1] = fz; }
  for (int c = 0; c < 4; ++c) {
    f4vec a1[4][2];
#pragma unroll
    for (int mi = 0; mi < 4; ++mi) { a1[mi][0] = fz; a1[mi][1] = fz; }
#pragma unroll
    for (int kk = 0; kk < 4; ++kk) {
      s8vec a0[4];
#pragma unroll
      for (int mi = 0; mi < 4; ++mi)
        a0[mi] = *(const s8vec*)(xs + (mi * 16 + li) * 128 + (((kk * 4 + g) ^ sl) << 3));
      s8vec bw[2];
#pragma unroll
      for (int nj = 0; nj < 2; ++nj)
        bw[nj] = *(const s8vec*)(w1 + (size_t)(c * 128 + h * 32 + nj * 16 + li) * 128 + kk * 32 + g * 8);
#pragma unroll
      for (int nj = 0; nj < 2; ++nj)
#pragma unroll
        for (int mi = 0; mi < 4; ++mi) a1[mi][nj] = MFMA(a0[mi], bw[nj], a1[mi][nj]);
    }
#pragma unroll
    for (int nj = 0; nj < 2; ++nj) {
      const float b1 = fc1b[c * 128 + h * 32 + nj * 16 + li];
      const int c8 = h * 4 + nj * 2 + (li >> 3);
#pragma unroll
      for (int mi = 0; mi < 4; ++mi)
#pragma unroll
        for (int r = 0; r < 4; ++r) {
          int i = mi * 16 + g * 4 + r;
          cs[i * 128 + ((c8 ^ (i & 7)) << 3) + sl] = (short)f2bf(gelu_t(a1[mi][nj][r] + b1));
        }
    }
    __syncthreads();  // chunk visible
#pragma unroll
    for (int kk = 0; kk < 4; ++kk) {
      s8vec a0[4];
#pragma unroll
      for (int mi = 0; mi < 4; ++mi)
        a0[mi] = *(const s8vec*)(cs + (mi * 16 + li) * 128 + (((kk * 4 + g) ^ sl) << 3));
      s8vec bw[2];
#pragma unroll
      for (int nj = 0; nj < 2; ++nj)
        bw[nj] = *(const s8vec*)(w2 + (size_t)(h * 32 + nj * 16 + li) * 512 + c * 128 + kk * 32 + g * 8);
#pragma unroll
      for (int nj = 0; nj < 2; ++nj)
#pragma unroll
        for (int mi = 0; mi < 4; ++mi) facc[mi][nj] = MFMA(a0[mi], bw[nj], facc[mi][nj]);
    }
    if (c != 3) __syncthreads();  // chunk reads done before overwrite
  }

  // ---- phase G: out = msa + fc2 + fc2b (single fp32 store, un-permuted) ----
#pragma unroll
  for (int nj = 0; nj < 2; ++nj) {
    const int col = h * 32 + nj * 16 + li;
    const float fb = fc2b[col];
#pragma unroll
    for (int mi = 0; mi < 4; ++mi)
#pragma unroll
      for (int r = 0; r < 4; ++r) {
        int i = mi * 16 + g * 4 + r;
        int sy = i >> 3, sx = i & 7;
        int py = (sy * 8 + hy + 8) & 63, px = (sx * 8 + wx + 8) & 63;
        size_t dst = ((size_t)(bb * 4096 + py * 64 + px)) * 128 + col;
        unsigned pk = msa_p[mi][nj][r >> 1];
        float mv = bf2f((unsigned short)((r & 1) ? (pk >> 16) : (pk & 0xffff)));
        out[dst] = mv + facc[mi][nj][r] + fb;
      }
  }
}

// ---------- launch ----------
extern "C" void kernel_launch(void* const* d_in, const int* in_sizes, int n_in,
                              void* d_out, int out_size, void* d_ws, size_t ws_size,
                              hipStream_t stream) {
  const float* x     = (const float*)d_in[0];
  const float* ln1w  = (const float*)d_in[1];
  const float* ln1b  = (const float*)d_in[2];
  const float* qkvw  = (const float*)d_in[3];
  const float* qkvb  = (const float*)d_in[4];
  const float* projw = (const float*)d_in[5];
  const float* projb = (const float*)d_in[6];
  const float* ln2w  = (const float*)d_in[7];
  const float* ln2b  = (const float*)d_in[8];
  const float* fc1w  = (const float*)d_in[9];
  const float* fc1b  = (const float*)d_in[10];
  const float* fc2w  = (const float*)d_in[11];
  const float* fc2b  = (const float*)d_in[12];

  short* wb = (short*)d_ws;  // bf16 weights: qkv@0, proj@49152, fc1@65536, fc2@131072
  float* out = (float*)d_out;

  wconv_k<<<768, 256, 0, stream>>>(qkvw, projw, fc1w, fc2w, wb);
  swin_k<<<2048, 256, 0, stream>>>(x, ln1w, ln1b, wb, qkvb, wb + 49152, projb,
                                   ln2w, ln2b, wb + 65536, fc1b, wb + 131072,
                                   fc2b, out);
}

// Round 7
// 285.912 us; speedup vs baseline: 1.0632x; 1.0255x over previous
//
#include <hip/hip_runtime.h>
#include <math.h>

typedef __attribute__((ext_vector_type(8))) short s8vec;
typedef __attribute__((ext_vector_type(8))) __bf16 bf8vec;
typedef __attribute__((ext_vector_type(4))) float f4vec;

__device__ __forceinline__ unsigned short f2bf(float f) {
  unsigned u = __float_as_uint(f);
  u += 0x7fffu + ((u >> 16) & 1u);  // RNE (finite values only)
  return (unsigned short)(u >> 16);
}
__device__ __forceinline__ float bf2f(unsigned short u) {
  return __uint_as_float(((unsigned)u) << 16);
}

__device__ __forceinline__ f4vec MFMA(s8vec a, s8vec b, f4vec c) {
  return __builtin_amdgcn_mfma_f32_16x16x32_bf16(
      __builtin_bit_cast(bf8vec, a), __builtin_bit_cast(bf8vec, b), c, 0, 0, 0);
}

// tanh-form GELU: |err| vs exact erf-GELU <= ~3e-3, below bf16 rounding of hid.
__device__ __forceinline__ float gelu_t(float v) {
  float u = 0.7978845608028654f * v * (1.f + 0.044715f * v * v);
  u = fminf(fmaxf(u, -15.f), 15.f);
  float e = __expf(2.f * u);
  return 0.5f * v * (1.f + (e - 1.f) / (e + 1.f));
}

// B=32, H=W=64, C=128, S=8, NH=4, HD=32; windows = 2048, tokens = 131072.

// ---------- K0: weight fp32 -> bf16 (qkv | proj | fc1 | fc2 concatenated) ----------
__global__ __launch_bounds__(256) void wconv_k(
    const float* __restrict__ qkvw, const float* __restrict__ projw,
    const float* __restrict__ f1w, const float* __restrict__ f2w,
    short* __restrict__ out) {
  int i = blockIdx.x * 256 + threadIdx.x;  // grid covers 196608 exactly
  float v;
  if (i < 49152)        v = qkvw[i];
  else if (i < 65536)   v = projw[i - 49152];
  else if (i < 131072)  v = f1w[i - 65536];
  else                  v = f2w[i - 131072];
  out[i] = (short)f2bf(v);
}

// ---------- K1: fully fused Swin block, ~32.25 KB LDS. 1 block = 1 window. ----------
// LDS (short idx): [0,8192) xs: LN1-out -> attn-out -> LN2-out
//                  [8192,16384) per-wave scratch (2048 ea) -> stats -> cs
//                  P overlay: head h at [h*4096, +4096) after barrier #2
// rowoff[64]: token -> global element offset of its (rolled) row; written in A.
__global__ __launch_bounds__(256) void swin_k(
    const float* __restrict__ x, const float* __restrict__ ln1w,
    const float* __restrict__ ln1b, const short* __restrict__ wq,
    const float* __restrict__ qkvb, const short* __restrict__ wp,
    const float* __restrict__ projb, const float* __restrict__ ln2w,
    const float* __restrict__ ln2b, const short* __restrict__ w1,
    const float* __restrict__ fc1b, const short* __restrict__ w2,
    const float* __restrict__ fc2b, float* __restrict__ out) {
  __shared__ short lds[16384];
  __shared__ int rowoff[64];
  short* xs = lds;
  float* statS = (float*)(lds + 8192);  // 256 f (alive only in phase E)
  float* statQ = statS + 256;
  short* cs = lds + 8192;               // MLP hid chunk [64][128]

  const int wi = blockIdx.x, tid = threadIdx.x;
  const int bb = wi >> 6, hy = (wi >> 3) & 7, wx = wi & 7;
  const f4vec fz = {0.f, 0.f, 0.f, 0.f};

  // ---- phase A: LN1 with roll+window gather (4 lanes per token) ----
  {
    const int t = tid >> 2, sub = tid & 3;
    const int sy = t >> 3, sx = t & 7;
    const int py = (sy * 8 + hy + 8) & 63, px = (sx * 8 + wx + 8) & 63;
    const int roff = (bb * 4096 + py * 64 + px) * 128;
    if (sub == 0) rowoff[t] = roff;
    const float* xr = x + (size_t)roff + sub * 32;
    float vv[32];
    float s = 0.f, sq = 0.f;
#pragma unroll
    for (int j = 0; j < 8; ++j) {
      float4 f = ((const float4*)xr)[j];
      vv[j * 4 + 0] = f.x; vv[j * 4 + 1] = f.y;
      vv[j * 4 + 2] = f.z; vv[j * 4 + 3] = f.w;
      s += f.x + f.y + f.z + f.w;
      sq += f.x * f.x + f.y * f.y + f.z * f.z + f.w * f.w;
    }
    s += __shfl_xor(s, 1);  s += __shfl_xor(s, 2);
    sq += __shfl_xor(sq, 1); sq += __shfl_xor(sq, 2);
    const float mean = s * 0.0078125f;
    const float rs = rsqrtf(sq * 0.0078125f - mean * mean + 1e-5f);
#pragma unroll
    for (int j8 = 0; j8 < 4; ++j8) {
      s8vec p;
#pragma unroll
      for (int e = 0; e < 8; ++e) {
        int c = sub * 32 + j8 * 8 + e;
        p[e] = (short)f2bf((vv[j8 * 8 + e] - mean) * rs * ln1w[c] + ln1b[c]);
      }
      *(s8vec*)(xs + t * 128 + (((sub * 4 + j8) ^ (t & 7)) << 3)) = p;
    }
  }
  __syncthreads();  // #1: xs (LN1) + rowoff ready

  const int h = tid >> 6, lane = tid & 63, g = lane >> 4, li = lane & 15;
  const int sl = li & 7;
  short* SCR = lds + 8192 + h * 2048;  // per-wave private scratch (4 KB)
  short* Pm = lds + h * 4096;          // per-head P [64][64] (after barrier #2)

  // ---- phase B: QKV via per-wave scratch transpose; weights batched up-front ----
  s8vec qf[4], kf[4], vf[2][2];
  auto qk_cycle = [&](const int T, s8vec* fr) {  // T=0 q, T=1 k
    s8vec bw[4][2];
#pragma unroll
    for (int kk = 0; kk < 4; ++kk)
#pragma unroll
      for (int n = 0; n < 2; ++n)
        bw[kk][n] = *(const s8vec*)(wq + (size_t)(h * 96 + T * 32 + n * 16 + li) * 128 + kk * 32 + g * 8);
    f4vec acc[4][2];
#pragma unroll
    for (int mi = 0; mi < 4; ++mi) { acc[mi][0] = fz; acc[mi][1] = fz; }
#pragma unroll
    for (int kk = 0; kk < 4; ++kk) {
      s8vec a0[4];
#pragma unroll
      for (int mi = 0; mi < 4; ++mi)
        a0[mi] = *(const s8vec*)(xs + (mi * 16 + li) * 128 + (((kk * 4 + g) ^ sl) << 3));
#pragma unroll
      for (int n = 0; n < 2; ++n)
#pragma unroll
        for (int mi = 0; mi < 4; ++mi) acc[mi][n] = MFMA(a0[mi], bw[kk][n], acc[mi][n]);
    }
    // scatter [token][hd(32)] granule-swizzled; same-wave LDS is in-order
#pragma unroll
    for (int n = 0; n < 2; ++n) {
      const float bias = qkvb[h * 96 + T * 32 + n * 16 + li];
#pragma unroll
      for (int mi = 0; mi < 4; ++mi)
#pragma unroll
        for (int r = 0; r < 4; ++r) {
          int t = mi * 16 + g * 4 + r;
          SCR[t * 32 + (((2 * n + (li >> 3)) ^ r) << 3) + sl] =
              (short)f2bf(acc[mi][n][r] + bias);
        }
    }
#pragma unroll
    for (int mi = 0; mi < 4; ++mi)
      fr[mi] = *(const s8vec*)(SCR + (mi * 16 + li) * 32 + ((g ^ (li & 3)) << 3));
  };
  qk_cycle(0, qf);
  qk_cycle(1, kf);
  {  // V cycle: layout [d(32)][token(64)] for PV B-fragments
    s8vec bw[4][2];
#pragma unroll
    for (int kk = 0; kk < 4; ++kk)
#pragma unroll
      for (int n = 0; n < 2; ++n)
        bw[kk][n] = *(const s8vec*)(wq + (size_t)(h * 96 + 64 + n * 16 + li) * 128 + kk * 32 + g * 8);
    f4vec acc[4][2];
#pragma unroll
    for (int mi = 0; mi < 4; ++mi) { acc[mi][0] = fz; acc[mi][1] = fz; }
#pragma unroll
    for (int kk = 0; kk < 4; ++kk) {
      s8vec a0[4];
#pragma unroll
      for (int mi = 0; mi < 4; ++mi)
        a0[mi] = *(const s8vec*)(xs + (mi * 16 + li) * 128 + (((kk * 4 + g) ^ sl) << 3));
#pragma unroll
      for (int n = 0; n < 2; ++n)
#pragma unroll
        for (int mi = 0; mi < 4; ++mi) acc[mi][n] = MFMA(a0[mi], bw[kk][n], acc[mi][n]);
    }
#pragma unroll
    for (int n = 0; n < 2; ++n) {
      const float bias = qkvb[h * 96 + 64 + n * 16 + li];
#pragma unroll
      for (int mi = 0; mi < 4; ++mi)
#pragma unroll
        for (int r = 0; r < 4; ++r) {
          int t = mi * 16 + g * 4 + r, d = n * 16 + li;
          SCR[d * 64 + (((t >> 3) ^ (li & 3)) << 3) + (t & 7)] =
              (short)f2bf(acc[mi][n][r] + bias);
        }
    }
#pragma unroll
    for (int di = 0; di < 2; ++di)
#pragma unroll
      for (int kk = 0; kk < 2; ++kk)
        vf[di][kk] = *(const s8vec*)(SCR + (di * 16 + li) * 64 + (((kk * 4 + g) ^ (li & 3)) << 3));
  }
  __syncthreads();  // #2: all xs/scratch reads done; P overlay now safe

  // ---- phase C: QK^T + residual-prefetch + softmax + P store + PV ----
  const float scale = 0.17677669529663687f;  // 1/sqrt(32); "+1.0" cancels
  f4vec e0[2][4], e1[2][4];
#pragma unroll
  for (int m2 = 0; m2 < 2; ++m2)
#pragma unroll
    for (int ni = 0; ni < 4; ++ni) { e0[m2][ni] = fz; e1[m2][ni] = fz; }
#pragma unroll
  for (int m2 = 0; m2 < 2; ++m2)
#pragma unroll
    for (int ni = 0; ni < 4; ++ni) e0[m2][ni] = MFMA(qf[m2], kf[ni], e0[m2][ni]);
#pragma unroll
  for (int m2 = 0; m2 < 2; ++m2)
#pragma unroll
    for (int ni = 0; ni < 4; ++ni) e1[m2][ni] = MFMA(qf[2 + m2], kf[ni], e1[m2][ni]);

  // prefetch residual x for phase D (independent; hidden under softmax+PV)
  int ro[4][4];
#pragma unroll
  for (int mi = 0; mi < 4; ++mi)
#pragma unroll
    for (int r = 0; r < 4; ++r) ro[mi][r] = rowoff[mi * 16 + g * 4 + r];
  float xres[4][2][4];
#pragma unroll
  for (int mi = 0; mi < 4; ++mi)
#pragma unroll
    for (int nj = 0; nj < 2; ++nj)
#pragma unroll
      for (int r = 0; r < 4; ++r)
        xres[mi][nj][r] = x[(size_t)ro[mi][r] + h * 32 + nj * 16 + li];

  auto smax = [&](f4vec (&e)[2][4], int hf) {
#pragma unroll
    for (int m2 = 0; m2 < 2; ++m2)
#pragma unroll
      for (int r = 0; r < 4; ++r) {
        float mx = e[m2][0][r];
#pragma unroll
        for (int ni = 1; ni < 4; ++ni) mx = fmaxf(mx, e[m2][ni][r]);
#pragma unroll
        for (int m = 1; m < 16; m <<= 1) mx = fmaxf(mx, __shfl_xor(mx, m));
        float pr[4], sm = 0.f;
#pragma unroll
        for (int ni = 0; ni < 4; ++ni) {
          pr[ni] = __expf((e[m2][ni][r] - mx) * scale);
          sm += pr[ni];
        }
#pragma unroll
        for (int m = 1; m < 16; m <<= 1) sm += __shfl_xor(sm, m);
        float inv = 1.0f / sm;
        int i = (hf * 2 + m2) * 16 + g * 4 + r;
#pragma unroll
        for (int ni = 0; ni < 4; ++ni) {
          int j = ni * 16 + li;
          Pm[i * 64 + (((j >> 3) ^ (i & 7)) << 3) + (j & 7)] = (short)f2bf(pr[ni] * inv);
        }
      }
  };
  smax(e0, 0);
  smax(e1, 1);

  f4vec o[4][2];
#pragma unroll
  for (int mi = 0; mi < 4; ++mi) { o[mi][0] = fz; o[mi][1] = fz; }
#pragma unroll
  for (int kk = 0; kk < 2; ++kk)
#pragma unroll
    for (int mi = 0; mi < 4; ++mi) {
      s8vec pa = *(const s8vec*)(Pm + (mi * 16 + li) * 64 + (((kk * 4 + g) ^ sl) << 3));
#pragma unroll
      for (int di = 0; di < 2; ++di) o[mi][di] = MFMA(pa, vf[di][kk], o[mi][di]);
    }
  __syncthreads();  // #3: all PV reads done (P overlaps xs rows); overlay safe

#pragma unroll
  for (int mi = 0; mi < 4; ++mi)
#pragma unroll
    for (int di = 0; di < 2; ++di)
#pragma unroll
      for (int r = 0; r < 4; ++r) {
        int i = mi * 16 + g * 4 + r;
        int c8 = h * 4 + di * 2 + (li >> 3);
        xs[i * 128 + ((c8 ^ (i & 7)) << 3) + sl] = (short)f2bf(o[mi][di][r]);
      }
  __syncthreads();  // #4: attn-out visible

  // ---- phase D: proj (weights batched) + bias + residual -> stats + packed msa ----
  s8vec bwp[4][2];
#pragma unroll
  for (int kk = 0; kk < 4; ++kk)
#pragma unroll
    for (int nj = 0; nj < 2; ++nj)
      bwp[kk][nj] = *(const s8vec*)(wp + (size_t)(h * 32 + nj * 16 + li) * 128 + kk * 32 + g * 8);
  f4vec pacc[4][2];
#pragma unroll
  for (int mi = 0; mi < 4; ++mi) { pacc[mi][0] = fz; pacc[mi][1] = fz; }
#pragma unroll
  for (int kk = 0; kk < 4; ++kk) {
    s8vec a0[4];
#pragma unroll
    for (int mi = 0; mi < 4; ++mi)
      a0[mi] = *(const s8vec*)(xs + (mi * 16 + li) * 128 + (((kk * 4 + g) ^ sl) << 3));
#pragma unroll
    for (int nj = 0; nj < 2; ++nj)
#pragma unroll
      for (int mi = 0; mi < 4; ++mi) pacc[mi][nj] = MFMA(a0[mi], bwp[kk][nj], pacc[mi][nj]);
  }
  const float pb0 = projb[h * 32 + li], pb1 = projb[h * 32 + 16 + li];
  unsigned msa_p[4][2][2];  // msa packed as bf16 pairs (r0|r1, r2|r3)
#pragma unroll
  for (int mi = 0; mi < 4; ++mi) {
    float m0[4], m1[4];
#pragma unroll
    for (int r = 0; r < 4; ++r) {
      m0[r] = bf2f(f2bf(xres[mi][0][r] + pacc[mi][0][r] + pb0));
      m1[r] = bf2f(f2bf(xres[mi][1][r] + pacc[mi][1][r] + pb1));
    }
    msa_p[mi][0][0] = ((unsigned)f2bf(m0[1]) << 16) | (unsigned)f2bf(m0[0]);
    msa_p[mi][0][1] = ((unsigned)f2bf(m0[3]) << 16) | (unsigned)f2bf(m0[2]);
    msa_p[mi][1][0] = ((unsigned)f2bf(m1[1]) << 16) | (unsigned)f2bf(m1[0]);
    msa_p[mi][1][1] = ((unsigned)f2bf(m1[3]) << 16) | (unsigned)f2bf(m1[2]);
#pragma unroll
    for (int r = 0; r < 4; ++r) {
      float s = m0[r] + m1[r];
      float q = m0[r] * m0[r] + m1[r] * m1[r];
#pragma unroll
      for (int m = 1; m < 16; m <<= 1) {
        s += __shfl_xor(s, m);
        q += __shfl_xor(q, m);
      }
      if (li == 0) {
        int i = mi * 16 + g * 4 + r;
        statS[i * 4 + h] = s;
        statQ[i * 4 + h] = q;
      }
    }
  }
  __syncthreads();  // #5: stats visible (scratch region otherwise dead)

  // ---- phase E: LN2 normalize (from packed msa) -> xs ----
  {
    const float lw0 = ln2w[h * 32 + li],      lb0 = ln2b[h * 32 + li];
    const float lw1 = ln2w[h * 32 + 16 + li], lb1 = ln2b[h * 32 + 16 + li];
#pragma unroll
    for (int mi = 0; mi < 4; ++mi)
#pragma unroll
      for (int r = 0; r < 4; ++r) {
        int i = mi * 16 + g * 4 + r;
        float4 s4 = *(const float4*)(statS + i * 4);
        float4 q4 = *(const float4*)(statQ + i * 4);
        float mean = (s4.x + s4.y + s4.z + s4.w) * 0.0078125f;
        float var = (q4.x + q4.y + q4.z + q4.w) * 0.0078125f - mean * mean;
        float rstd = rsqrtf(var + 1e-5f);
        unsigned p0 = msa_p[mi][0][r >> 1], p1 = msa_p[mi][1][r >> 1];
        float v0 = bf2f((unsigned short)((r & 1) ? (p0 >> 16) : (p0 & 0xffff)));
        float v1 = bf2f((unsigned short)((r & 1) ? (p1 >> 16) : (p1 & 0xffff)));
        float n0 = (v0 - mean) * rstd * lw0 + lb0;
        float n1 = (v1 - mean) * rstd * lw1 + lb1;
        xs[i * 128 + (((h * 4 + (li >> 3)) ^ (i & 7)) << 3) + sl] = (short)f2bf(n0);
        xs[i * 128 + (((h * 4 + 2 + (li >> 3)) ^ (i & 7)) << 3) + sl] = (short)f2bf(n1);
      }
  }
  __syncthreads();  // #6: xs (LN2) ready; stats dead; cs overlay safe

  // ---- phase F: MLP, hid chunked 4 x 128 cols through cs (16 KB) ----
  f4vec facc[4][2];
#pragma unroll
  for (int mi = 0; mi < 4; ++mi) { facc[mi][0] = fz; facc[mi][1] = fz; }
#pragma unroll 1
  for (int c = 0; c < 4; ++c) {
    s8vec bw1[4][2];
#pragma unroll
    for (int kk = 0; kk < 4; ++kk)
#pragma unroll
      for (int nj = 0; nj < 2; ++nj)
        bw1[kk][nj] = *(const s8vec*)(w1 + (size_t)(c * 128 + h * 32 + nj * 16 + li) * 128 + kk * 32 + g * 8);
    f4vec a1[4][2];
#pragma unroll
    for (int mi = 0; mi < 4; ++mi) { a1[mi][0] = fz; a1[mi][1] = fz; }
#pragma unroll
    for (int kk = 0; kk < 4; ++kk) {
      s8vec a0[4];
#pragma unroll
      for (int mi = 0; mi < 4; ++mi)
        a0[mi] = *(const s8vec*)(xs + (mi * 16 + li) * 128 + (((kk * 4 + g) ^ sl) << 3));
#pragma unroll
      for (int nj = 0; nj < 2; ++nj)
#pragma unroll
        for (int mi = 0; mi < 4; ++mi) a1[mi][nj] = MFMA(a0[mi], bw1[kk][nj], a1[mi][nj]);
    }
#pragma unroll
    for (int nj = 0; nj < 2; ++nj) {
      const float b1 = fc1b[c * 128 + h * 32 + nj * 16 + li];
      const int c8 = h * 4 + nj * 2 + (li >> 3);
#pragma unroll
      for (int mi = 0; mi < 4; ++mi)
#pragma unroll
        for (int r = 0; r < 4; ++r) {
          int i = mi * 16 + g * 4 + r;
          cs[i * 128 + ((c8 ^ (i & 7)) << 3) + sl] = (short)f2bf(gelu_t(a1[mi][nj][r] + b1));
        }
    }
    // FC2 weights issued pre-barrier: latency hidden under barrier + others' FC1
    s8vec bw2[4][2];
#pragma unroll
    for (int kk = 0; kk < 4; ++kk)
#pragma unroll
      for (int nj = 0; nj < 2; ++nj)
        bw2[kk][nj] = *(const s8vec*)(w2 + (size_t)(h * 32 + nj * 16 + li) * 512 + c * 128 + kk * 32 + g * 8);
    __syncthreads();  // chunk visible
#pragma unroll
    for (int kk = 0; kk < 4; ++kk) {
      s8vec a0[4];
#pragma unroll
      for (int mi = 0; mi < 4; ++mi)
        a0[mi] = *(const s8vec*)(cs + (mi * 16 + li) * 128 + (((kk * 4 + g) ^ sl) << 3));
#pragma unroll
      for (int nj = 0; nj < 2; ++nj)
#pragma unroll
        for (int mi = 0; mi < 4; ++mi) facc[mi][nj] = MFMA(a0[mi], bw2[kk][nj], facc[mi][nj]);
    }
    if (c != 3) __syncthreads();  // chunk reads done before overwrite
  }

  // ---- phase G: out = msa + fc2 + fc2b (single fp32 store, un-permuted) ----
#pragma unroll
  for (int nj = 0; nj < 2; ++nj) {
    const int col = h * 32 + nj * 16 + li;
    const float fb = fc2b[col];
#pragma unroll
    for (int mi = 0; mi < 4; ++mi)
#pragma unroll
      for (int r = 0; r < 4; ++r) {
        unsigned pk = msa_p[mi][nj][r >> 1];
        float mv = bf2f((unsigned short)((r & 1) ? (pk >> 16) : (pk & 0xffff)));
        out[(size_t)ro[mi][r] + col] = mv + facc[mi][nj][r] + fb;
      }
  }
}

// ---------- launch ----------
extern "C" void kernel_launch(void* const* d_in, const int* in_sizes, int n_in,
                              void* d_out, int out_size, void* d_ws, size_t ws_size,
                              hipStream_t stream) {
  const float* x     = (const float*)d_in[0];
  const float* ln1w  = (const float*)d_in[1];
  const float* ln1b  = (const float*)d_in[2];
  const float* qkvw  = (const float*)d_in[3];
  const float* qkvb  = (const float*)d_in[4];
  const float* projw = (const float*)d_in[5];
  const float* projb = (const float*)d_in[6];
  const float* ln2w  = (const float*)d_in[7];
  const float* ln2b  = (const float*)d_in[8];
  const float* fc1w  = (const float*)d_in[9];
  const float* fc1b  = (const float*)d_in[10];
  const float* fc2w  = (const float*)d_in[11];
  const float* fc2b  = (const float*)d_in[12];

  short* wb = (short*)d_ws;  // bf16 weights: qkv@0, proj@49152, fc1@65536, fc2@131072
  float* out = (float*)d_out;

  wconv_k<<<768, 256, 0, stream>>>(qkvw, projw, fc1w, fc2w, wb);
  swin_k<<<2048, 256, 0, stream>>>(x, ln1w, ln1b, wb, qkvb, wb + 49152, projb,
                                   ln2w, ln2b, wb + 65536, fc1b, wb + 131072,
                                   fc2b, out);
}

// Round 9
// 192.534 us; speedup vs baseline: 1.5788x; 1.4850x over previous
//
#include <hip/hip_runtime.h>
#include <math.h>

typedef __attribute__((ext_vector_type(8))) short s8vec;
typedef __attribute__((ext_vector_type(8))) __bf16 bf8vec;
typedef __attribute__((ext_vector_type(4))) float f4vec;

__device__ __forceinline__ unsigned short f2bf(float f) {
  unsigned u = __float_as_uint(f);
  u += 0x7fffu + ((u >> 16) & 1u);  // RNE (finite values only)
  return (unsigned short)(u >> 16);
}
__device__ __forceinline__ float bf2f(unsigned short u) {
  return __uint_as_float(((unsigned)u) << 16);
}

__device__ __forceinline__ f4vec MFMA(s8vec a, s8vec b, f4vec c) {
  return __builtin_amdgcn_mfma_f32_16x16x32_bf16(
      __builtin_bit_cast(bf8vec, a), __builtin_bit_cast(bf8vec, b), c, 0, 0, 0);
}

// tanh-form GELU: |err| vs exact erf-GELU <= ~3e-3, below bf16 rounding of hid.
__device__ __forceinline__ float gelu_t(float v) {
  float u = 0.7978845608028654f * v * (1.f + 0.044715f * v * v);
  u = fminf(fmaxf(u, -15.f), 15.f);
  float e = __expf(2.f * u);
  return 0.5f * v * (1.f + (e - 1.f) / (e + 1.f));
}

// B=32, H=W=64, C=128, S=8, NH=4, HD=32; windows = 2048, tokens = 131072.

// ---------- K0: weight fp32 -> bf16 (qkv | proj | fc1 | fc2 concatenated) ----------
__global__ __launch_bounds__(256) void wconv_k(
    const float* __restrict__ qkvw, const float* __restrict__ projw,
    const float* __restrict__ f1w, const float* __restrict__ f2w,
    short* __restrict__ out) {
  int i = blockIdx.x * 256 + threadIdx.x;  // grid covers 196608 exactly
  float v;
  if (i < 49152)        v = qkvw[i];
  else if (i < 65536)   v = projw[i - 49152];
  else if (i < 131072)  v = f1w[i - 65536];
  else                  v = f2w[i - 131072];
  out[i] = (short)f2bf(v);
}

// ---------- K1: fully fused Swin block, ~32.25 KB LDS. 1 block = 1 window. ----------
// __launch_bounds__(256,2): cap unified VGPR+AGPR at 256/wave -> 2 waves/SIMD
// (all prior rounds ran 1 wave/SIMD: unified total > 256 despite VGPR_Count ~148).
// LDS (short idx): [0,8192) xs: LN1-out -> attn-out -> LN2-out
//                  [8192,16384) per-wave scratch (2048 ea) -> stats -> cs
//                  P overlay: head h at [h*4096, +4096) after barrier #2
__global__ __launch_bounds__(256, 2) void swin_k(
    const float* __restrict__ x, const float* __restrict__ ln1w,
    const float* __restrict__ ln1b, const short* __restrict__ wq,
    const float* __restrict__ qkvb, const short* __restrict__ wp,
    const float* __restrict__ projb, const float* __restrict__ ln2w,
    const float* __restrict__ ln2b, const short* __restrict__ w1,
    const float* __restrict__ fc1b, const short* __restrict__ w2,
    const float* __restrict__ fc2b, float* __restrict__ out) {
  __shared__ short lds[16384];
  __shared__ int rowoff[64];
  short* xs = lds;
  float* statS = (float*)(lds + 8192);  // 256 f (alive only in phase D/E)
  float* statQ = statS + 256;
  short* cs = lds + 8192;               // MLP hid chunk [64][128]

  const int wi = blockIdx.x, tid = threadIdx.x;
  const int bb = wi >> 6, hy = (wi >> 3) & 7, wx = wi & 7;
  const f4vec fz = {0.f, 0.f, 0.f, 0.f};

  // ---- phase A: LN1 with roll+window gather (4 lanes per token) ----
  {
    const int t = tid >> 2, sub = tid & 3;
    const int sy = t >> 3, sx = t & 7;
    const int py = (sy * 8 + hy + 8) & 63, px = (sx * 8 + wx + 8) & 63;
    const int roff = (bb * 4096 + py * 64 + px) * 128;
    if (sub == 0) rowoff[t] = roff;
    const float* xr = x + (size_t)roff + sub * 32;
    float vv[32];
    float s = 0.f, sq = 0.f;
#pragma unroll
    for (int j = 0; j < 8; ++j) {
      float4 f = ((const float4*)xr)[j];
      vv[j * 4 + 0] = f.x; vv[j * 4 + 1] = f.y;
      vv[j * 4 + 2] = f.z; vv[j * 4 + 3] = f.w;
      s += f.x + f.y + f.z + f.w;
      sq += f.x * f.x + f.y * f.y + f.z * f.z + f.w * f.w;
    }
    s += __shfl_xor(s, 1);  s += __shfl_xor(s, 2);
    sq += __shfl_xor(sq, 1); sq += __shfl_xor(sq, 2);
    const float mean = s * 0.0078125f;
    const float rs = rsqrtf(sq * 0.0078125f - mean * mean + 1e-5f);
#pragma unroll
    for (int j8 = 0; j8 < 4; ++j8) {
      s8vec p;
#pragma unroll
      for (int e = 0; e < 8; ++e) {
        int c = sub * 32 + j8 * 8 + e;
        p[e] = (short)f2bf((vv[j8 * 8 + e] - mean) * rs * ln1w[c] + ln1b[c]);
      }
      *(s8vec*)(xs + t * 128 + (((sub * 4 + j8) ^ (t & 7)) << 3)) = p;
    }
  }
  __syncthreads();  // #1: xs (LN1) + rowoff ready

  const int h = tid >> 6, lane = tid & 63, g = lane >> 4, li = lane & 15;
  const int sl = li & 7;
  short* SCR = lds + 8192 + h * 2048;  // per-wave private scratch (4 KB)
  short* Pm = lds + h * 4096;          // per-head P [64][64] (after barrier #2)

  // ---- phase B: QKV via per-wave scratch transpose; weights batched up-front ----
  s8vec qf[4], kf[4], vf[2][2];
  auto qk_cycle = [&](const int T, s8vec* fr) {  // T=0 q, T=1 k
    s8vec bw[4][2];
#pragma unroll
    for (int kk = 0; kk < 4; ++kk)
#pragma unroll
      for (int n = 0; n < 2; ++n)
        bw[kk][n] = *(const s8vec*)(wq + (size_t)(h * 96 + T * 32 + n * 16 + li) * 128 + kk * 32 + g * 8);
    f4vec acc[4][2];
#pragma unroll
    for (int mi = 0; mi < 4; ++mi) { acc[mi][0] = fz; acc[mi][1] = fz; }
#pragma unroll
    for (int kk = 0; kk < 4; ++kk) {
      s8vec a0[4];
#pragma unroll
      for (int mi = 0; mi < 4; ++mi)
        a0[mi] = *(const s8vec*)(xs + (mi * 16 + li) * 128 + (((kk * 4 + g) ^ sl) << 3));
#pragma unroll
      for (int n = 0; n < 2; ++n)
#pragma unroll
        for (int mi = 0; mi < 4; ++mi) acc[mi][n] = MFMA(a0[mi], bw[kk][n], acc[mi][n]);
    }
    // scatter [token][hd(32)] granule-swizzled; same-wave LDS is in-order
#pragma unroll
    for (int n = 0; n < 2; ++n) {
      const float bias = qkvb[h * 96 + T * 32 + n * 16 + li];
#pragma unroll
      for (int mi = 0; mi < 4; ++mi)
#pragma unroll
        for (int r = 0; r < 4; ++r) {
          int t = mi * 16 + g * 4 + r;
          SCR[t * 32 + (((2 * n + (li >> 3)) ^ r) << 3) + sl] =
              (short)f2bf(acc[mi][n][r] + bias);
        }
    }
#pragma unroll
    for (int mi = 0; mi < 4; ++mi)
      fr[mi] = *(const s8vec*)(SCR + (mi * 16 + li) * 32 + ((g ^ (li & 3)) << 3));
  };
  qk_cycle(0, qf);
  qk_cycle(1, kf);
  {  // V cycle: layout [d(32)][token(64)] for PV B-fragments
    s8vec bw[4][2];
#pragma unroll
    for (int kk = 0; kk < 4; ++kk)
#pragma unroll
      for (int n = 0; n < 2; ++n)
        bw[kk][n] = *(const s8vec*)(wq + (size_t)(h * 96 + 64 + n * 16 + li) * 128 + kk * 32 + g * 8);
    f4vec acc[4][2];
#pragma unroll
    for (int mi = 0; mi < 4; ++mi) { acc[mi][0] = fz; acc[mi][1] = fz; }
#pragma unroll
    for (int kk = 0; kk < 4; ++kk) {
      s8vec a0[4];
#pragma unroll
      for (int mi = 0; mi < 4; ++mi)
        a0[mi] = *(const s8vec*)(xs + (mi * 16 + li) * 128 + (((kk * 4 + g) ^ sl) << 3));
#pragma unroll
      for (int n = 0; n < 2; ++n)
#pragma unroll
        for (int mi = 0; mi < 4; ++mi) acc[mi][n] = MFMA(a0[mi], bw[kk][n], acc[mi][n]);
    }
#pragma unroll
    for (int n = 0; n < 2; ++n) {
      const float bias = qkvb[h * 96 + 64 + n * 16 + li];
#pragma unroll
      for (int mi = 0; mi < 4; ++mi)
#pragma unroll
        for (int r = 0; r < 4; ++r) {
          int t = mi * 16 + g * 4 + r, d = n * 16 + li;
          SCR[d * 64 + (((t >> 3) ^ (li & 3)) << 3) + (t & 7)] =
              (short)f2bf(acc[mi][n][r] + bias);
        }
    }
#pragma unroll
    for (int di = 0; di < 2; ++di)
#pragma unroll
      for (int kk = 0; kk < 2; ++kk)
        vf[di][kk] = *(const s8vec*)(SCR + (di * 16 + li) * 64 + (((kk * 4 + g) ^ (li & 3)) << 3));
  }
  __syncthreads();  // #2: all xs/scratch reads done; P overlay now safe

  // ---- phase C: QK^T (hf-looped: one e[2][4] live) + softmax + P + PV ----
  const float scale = 0.17677669529663687f;  // 1/sqrt(32); "+1.0" cancels
#pragma unroll
  for (int hf = 0; hf < 2; ++hf) {
    f4vec e[2][4];
#pragma unroll
    for (int m2 = 0; m2 < 2; ++m2)
#pragma unroll
      for (int ni = 0; ni < 4; ++ni) e[m2][ni] = fz;
#pragma unroll
    for (int m2 = 0; m2 < 2; ++m2)
#pragma unroll
      for (int ni = 0; ni < 4; ++ni)
        e[m2][ni] = MFMA(qf[hf * 2 + m2], kf[ni], e[m2][ni]);
#pragma unroll
    for (int m2 = 0; m2 < 2; ++m2)
#pragma unroll
      for (int r = 0; r < 4; ++r) {
        float mx = e[m2][0][r];
#pragma unroll
        for (int ni = 1; ni < 4; ++ni) mx = fmaxf(mx, e[m2][ni][r]);
#pragma unroll
        for (int m = 1; m < 16; m <<= 1) mx = fmaxf(mx, __shfl_xor(mx, m));
        float pr[4], sm = 0.f;
#pragma unroll
        for (int ni = 0; ni < 4; ++ni) {
          pr[ni] = __expf((e[m2][ni][r] - mx) * scale);
          sm += pr[ni];
        }
#pragma unroll
        for (int m = 1; m < 16; m <<= 1) sm += __shfl_xor(sm, m);
        float inv = 1.0f / sm;
        int i = (hf * 2 + m2) * 16 + g * 4 + r;
#pragma unroll
        for (int ni = 0; ni < 4; ++ni) {
          int j = ni * 16 + li;
          Pm[i * 64 + (((j >> 3) ^ (i & 7)) << 3) + (j & 7)] = (short)f2bf(pr[ni] * inv);
        }
      }
  }
  f4vec o[4][2];
#pragma unroll
  for (int mi = 0; mi < 4; ++mi) { o[mi][0] = fz; o[mi][1] = fz; }
#pragma unroll
  for (int kk = 0; kk < 2; ++kk)
#pragma unroll
    for (int mi = 0; mi < 4; ++mi) {
      s8vec pa = *(const s8vec*)(Pm + (mi * 16 + li) * 64 + (((kk * 4 + g) ^ sl) << 3));
#pragma unroll
      for (int di = 0; di < 2; ++di) o[mi][di] = MFMA(pa, vf[di][kk], o[mi][di]);
    }
  __syncthreads();  // #3: all PV reads done (P overlaps xs rows); overlay safe

#pragma unroll
  for (int mi = 0; mi < 4; ++mi)
#pragma unroll
    for (int di = 0; di < 2; ++di)
#pragma unroll
      for (int r = 0; r < 4; ++r) {
        int i = mi * 16 + g * 4 + r;
        int c8 = h * 4 + di * 2 + (li >> 3);
        xs[i * 128 + ((c8 ^ (i & 7)) << 3) + sl] = (short)f2bf(o[mi][di][r]);
      }
  __syncthreads();  // #4: attn-out visible

  // ---- phase D: residual batch-load + proj (weights batched) -> stats + msa ----
  float xres[4][2][4];
#pragma unroll
  for (int mi = 0; mi < 4; ++mi)
#pragma unroll
    for (int r = 0; r < 4; ++r) {
      const int roff = rowoff[mi * 16 + g * 4 + r];
#pragma unroll
      for (int nj = 0; nj < 2; ++nj)
        xres[mi][nj][r] = x[(size_t)roff + h * 32 + nj * 16 + li];
    }
  s8vec bwp[4][2];
#pragma unroll
  for (int kk = 0; kk < 4; ++kk)
#pragma unroll
    for (int nj = 0; nj < 2; ++nj)
      bwp[kk][nj] = *(const s8vec*)(wp + (size_t)(h * 32 + nj * 16 + li) * 128 + kk * 32 + g * 8);
  f4vec pacc[4][2];
#pragma unroll
  for (int mi = 0; mi < 4; ++mi) { pacc[mi][0] = fz; pacc[mi][1] = fz; }
#pragma unroll
  for (int kk = 0; kk < 4; ++kk) {
    s8vec a0[4];
#pragma unroll
    for (int mi = 0; mi < 4; ++mi)
      a0[mi] = *(const s8vec*)(xs + (mi * 16 + li) * 128 + (((kk * 4 + g) ^ sl) << 3));
#pragma unroll
    for (int nj = 0; nj < 2; ++nj)
#pragma unroll
      for (int mi = 0; mi < 4; ++mi) pacc[mi][nj] = MFMA(a0[mi], bwp[kk][nj], pacc[mi][nj]);
  }
  const float pb0 = projb[h * 32 + li], pb1 = projb[h * 32 + 16 + li];
  unsigned msa_p[4][2][2];  // msa packed as bf16 pairs (r0|r1, r2|r3)
#pragma unroll
  for (int mi = 0; mi < 4; ++mi) {
    float m0[4], m1[4];
#pragma unroll
    for (int r = 0; r < 4; ++r) {
      m0[r] = bf2f(f2bf(xres[mi][0][r] + pacc[mi][0][r] + pb0));
      m1[r] = bf2f(f2bf(xres[mi][1][r] + pacc[mi][1][r] + pb1));
    }
    msa_p[mi][0][0] = ((unsigned)f2bf(m0[1]) << 16) | (unsigned)f2bf(m0[0]);
    msa_p[mi][0][1] = ((unsigned)f2bf(m0[3]) << 16) | (unsigned)f2bf(m0[2]);
    msa_p[mi][1][0] = ((unsigned)f2bf(m1[1]) << 16) | (unsigned)f2bf(m1[0]);
    msa_p[mi][1][1] = ((unsigned)f2bf(m1[3]) << 16) | (unsigned)f2bf(m1[2]);
#pragma unroll
    for (int r = 0; r < 4; ++r) {
      float s = m0[r] + m1[r];
      float q = m0[r] * m0[r] + m1[r] * m1[r];
#pragma unroll
      for (int m = 1; m < 16; m <<= 1) {
        s += __shfl_xor(s, m);
        q += __shfl_xor(q, m);
      }
      if (li == 0) {
        int i = mi * 16 + g * 4 + r;
        statS[i * 4 + h] = s;
        statQ[i * 4 + h] = q;
      }
    }
  }
  __syncthreads();  // #5: stats visible (scratch region otherwise dead)

  // ---- phase E: LN2 normalize (from packed msa) -> xs ----
  {
    const float lw0 = ln2w[h * 32 + li],      lb0 = ln2b[h * 32 + li];
    const float lw1 = ln2w[h * 32 + 16 + li], lb1 = ln2b[h * 32 + 16 + li];
#pragma unroll
    for (int mi = 0; mi < 4; ++mi)
#pragma unroll
      for (int r = 0; r < 4; ++r) {
        int i = mi * 16 + g * 4 + r;
        float4 s4 = *(const float4*)(statS + i * 4);
        float4 q4 = *(const float4*)(statQ + i * 4);
        float mean = (s4.x + s4.y + s4.z + s4.w) * 0.0078125f;
        float var = (q4.x + q4.y + q4.z + q4.w) * 0.0078125f - mean * mean;
        float rstd = rsqrtf(var + 1e-5f);
        unsigned p0 = msa_p[mi][0][r >> 1], p1 = msa_p[mi][1][r >> 1];
        float v0 = bf2f((unsigned short)((r & 1) ? (p0 >> 16) : (p0 & 0xffff)));
        float v1 = bf2f((unsigned short)((r & 1) ? (p1 >> 16) : (p1 & 0xffff)));
        float n0 = (v0 - mean) * rstd * lw0 + lb0;
        float n1 = (v1 - mean) * rstd * lw1 + lb1;
        xs[i * 128 + (((h * 4 + (li >> 3)) ^ (i & 7)) << 3) + sl] = (short)f2bf(n0);
        xs[i * 128 + (((h * 4 + 2 + (li >> 3)) ^ (i & 7)) << 3) + sl] = (short)f2bf(n1);
      }
  }
  __syncthreads();  // #6: xs (LN2) ready; stats dead; cs overlay safe

  // ---- phase F: MLP, hid chunked 4 x 128 cols through cs (16 KB) ----
  f4vec facc[4][2];
#pragma unroll
  for (int mi = 0; mi < 4; ++mi) { facc[mi][0] = fz; facc[mi][1] = fz; }
#pragma unroll 1
  for (int c = 0; c < 4; ++c) {
    s8vec bw1[4][2];
#pragma unroll
    for (int kk = 0; kk < 4; ++kk)
#pragma unroll
      for (int nj = 0; nj < 2; ++nj)
        bw1[kk][nj] = *(const s8vec*)(w1 + (size_t)(c * 128 + h * 32 + nj * 16 + li) * 128 + kk * 32 + g * 8);
    f4vec a1[4][2];
#pragma unroll
    for (int mi = 0; mi < 4; ++mi) { a1[mi][0] = fz; a1[mi][1] = fz; }
#pragma unroll
    for (int kk = 0; kk < 4; ++kk) {
      s8vec a0[4];
#pragma unroll
      for (int mi = 0; mi < 4; ++mi)
        a0[mi] = *(const s8vec*)(xs + (mi * 16 + li) * 128 + (((kk * 4 + g) ^ sl) << 3));
#pragma unroll
      for (int nj = 0; nj < 2; ++nj)
#pragma unroll
        for (int mi = 0; mi < 4; ++mi) a1[mi][nj] = MFMA(a0[mi], bw1[kk][nj], a1[mi][nj]);
    }
#pragma unroll
    for (int nj = 0; nj < 2; ++nj) {
      const float b1 = fc1b[c * 128 + h * 32 + nj * 16 + li];
      const int c8 = h * 4 + nj * 2 + (li >> 3);
#pragma unroll
      for (int mi = 0; mi < 4; ++mi)
#pragma unroll
        for (int r = 0; r < 4; ++r) {
          int i = mi * 16 + g * 4 + r;
          cs[i * 128 + ((c8 ^ (i & 7)) << 3) + sl] = (short)f2bf(gelu_t(a1[mi][nj][r] + b1));
        }
    }
    // FC2 weights issued pre-barrier: latency hidden under barrier + others' FC1
    s8vec bw2[4][2];
#pragma unroll
    for (int kk = 0; kk < 4; ++kk)
#pragma unroll
      for (int nj = 0; nj < 2; ++nj)
        bw2[kk][nj] = *(const s8vec*)(w2 + (size_t)(h * 32 + nj * 16 + li) * 512 + c * 128 + kk * 32 + g * 8);
    __syncthreads();  // chunk visible
#pragma unroll
    for (int kk = 0; kk < 4; ++kk) {
      s8vec a0[4];
#pragma unroll
      for (int mi = 0; mi < 4; ++mi)
        a0[mi] = *(const s8vec*)(cs + (mi * 16 + li) * 128 + (((kk * 4 + g) ^ sl) << 3));
#pragma unroll
      for (int nj = 0; nj < 2; ++nj)
#pragma unroll
        for (int mi = 0; mi < 4; ++mi) facc[mi][nj] = MFMA(a0[mi], bw2[kk][nj], facc[mi][nj]);
    }
    if (c != 3) __syncthreads();  // chunk reads done before overwrite
  }

  // ---- phase G: out = msa + fc2 + fc2b (single fp32 store, un-permuted) ----
#pragma unroll
  for (int nj = 0; nj < 2; ++nj) {
    const int col = h * 32 + nj * 16 + li;
    const float fb = fc2b[col];
#pragma unroll
    for (int mi = 0; mi < 4; ++mi)
#pragma unroll
      for (int r = 0; r < 4; ++r) {
        const int roff = rowoff[mi * 16 + g * 4 + r];
        unsigned pk = msa_p[mi][nj][r >> 1];
        float mv = bf2f((unsigned short)((r & 1) ? (pk >> 16) : (pk & 0xffff)));
        out[(size_t)roff + col] = mv + facc[mi][nj][r] + fb;
      }
  }
}

// ---------- launch ----------
extern "C" void kernel_launch(void* const* d_in, const int* in_sizes, int n_in,
                              void* d_out, int out_size, void* d_ws, size_t ws_size,
                              hipStream_t stream) {
  const float* x     = (const float*)d_in[0];
  const float* ln1w  = (const float*)d_in[1];
  const float* ln1b  = (const float*)d_in[2];
  const float* qkvw  = (const float*)d_in[3];
  const float* qkvb  = (const float*)d_in[4];
  const float* projw = (const float*)d_in[5];
  const float* projb = (const float*)d_in[6];
  const float* ln2w  = (const float*)d_in[7];
  const float* ln2b  = (const float*)d_in[8];
  const float* fc1w  = (const float*)d_in[9];
  const float* fc1b  = (const float*)d_in[10];
  const float* fc2w  = (const float*)d_in[11];
  const float* fc2b  = (const float*)d_in[12];

  short* wb = (short*)d_ws;  // bf16 weights: qkv@0, proj@49152, fc1@65536, fc2@131072
  float* out = (float*)d_out;

  wconv_k<<<768, 256, 0, stream>>>(qkvw, projw, fc1w, fc2w, wb);
  swin_k<<<2048, 256, 0, stream>>>(x, ln1w, ln1b, wb, qkvb, wb + 49152, projb,
                                   ln2w, ln2b, wb + 65536, fc1b, wb + 131072,
                                   fc2b, out);
}